// Round 8
// baseline (290.004 us; speedup 1.0000x reference)
//
#include <hip/hip_runtime.h>
#include <hip/hip_bf16.h>

#define HH 1024
#define AA 512
#define BB 32
#define SS 1024
#define TN 1024
#define M_ENC (SS*BB)
#define M_TOT ((SS+TN)*BB)
#define NCH 8

// e1_gemm LDS geometry: buffer = [A 128x72B][B 32KB]
#define ABYTES 9216
#define BUFSZ  41984

typedef __attribute__((ext_vector_type(8))) short short8;
typedef __attribute__((ext_vector_type(4))) float f4;

union bfu { __hip_bfloat16 h; unsigned short u; };
__device__ __forceinline__ unsigned int f2bu(float x) {
  bfu t; t.h = __float2bfloat16(x); return (unsigned int)t.u;
}
__device__ __forceinline__ unsigned short f2b(float x) {
  bfu t; t.h = __float2bfloat16(x); return t.u;
}
__device__ __forceinline__ float tanh_fast(float x) {
  float e = __expf(2.f * x);
  return 1.f - 2.f / (e + 1.f);
}

// ---- one-time W -> bf16 fragment-order repack ------------------------------
// Wc layout: frag id t = ((kb*32 + rg)*64 + lane), 8 bf16 per frag.
// fragment holds W[rg*16 + (lane&15)][kb*32 + (lane>>4)*8 + j]
__global__ void wprep(const float* __restrict__ W, unsigned short* __restrict__ Wc) {
  const int t = blockIdx.x * 256 + threadIdx.x;     // 0..65535
  const int lane = t & 63;
  const int rg = (t >> 6) & 31;
  const int kb = t >> 11;
  const int row = rg * 16 + (lane & 15);
  const int k = kb * 32 + ((lane >> 4) << 3);
  const float* src = W + (size_t)row * HH + k;
  f4 v0 = *(const f4*)(src);
  f4 v1 = *(const f4*)(src + 4);
  short8 o;
  o[0] = f2b(v0[0]); o[1] = f2b(v0[1]); o[2] = f2b(v0[2]); o[3] = f2b(v0[3]);
  o[4] = f2b(v1[0]); o[5] = f2b(v1[1]); o[6] = f2b(v1[2]); o[7] = f2b(v1[3]);
  *(short8*)(Wc + (size_t)t * 8) = o;
}

// ---- poly coefficients: sum_a W4[2A+a]*tanh(x*W3[a]) = C0*x + C1*x^3 + C2*x^5
__global__ void poly_prep(const float* __restrict__ W3, const float* __restrict__ W4,
                          float* __restrict__ C) {
  __shared__ float r1[AA], r3[AA], r5[AA];
  const int a = threadIdx.x;  // 512
  const float w = W3[a], u = W4[2 * AA + a];
  const float w2 = w * w;
  r1[a] = u * w;
  r3[a] = u * w * w2;
  r5[a] = u * w * w2 * w2;
  __syncthreads();
  for (int off = 256; off > 0; off >>= 1) {
    if (a < off) { r1[a] += r1[a + off]; r3[a] += r3[a + off]; r5[a] += r5[a + off]; }
    __syncthreads();
  }
  if (a == 0) { C[0] = r1[0]; C[1] = -r3[0] / 3.f; C[2] = r5[0] * (2.f / 15.f); }
}

// ---- big fused GEMM: e1[row] = sum_a V[a]*tanh( X[row,:] . W[a,:] ) --------
// BM=128, 1024 threads = 16 waves (2 rowg x 8 colg), wave tile 64x64, acc[4][4].
// 3-buffer pipeline, K-loop unrolled x3 (compile-time buffer offsets), uniform
// all-thread A staging (1 f4 + 1 ds_write_b64 each), A written at TOP of the
// NEXT step (full step of latency slack), counted vmcnt(3) + raw s_barrier.
// A LDS stride 72B (pad: <=2-way, free). B fragment-ordered via global_load_lds.
__global__ __launch_bounds__(1024, 4)
void e1_gemm(const float* __restrict__ enc, const float* __restrict__ h0,
             const unsigned short* __restrict__ W1c, const unsigned short* __restrict__ W5c,
             const float* __restrict__ W4, const float* __restrict__ W8,
             float* __restrict__ e1) {
  const int wg   = blockIdx.x;        // 512 blocks, 128 rows each
  const int tid  = threadIdx.x;       // 1024
  const int lane = tid & 63;
  const int wave = tid >> 6;          // 0..15
  const int rowg = wave >> 3;         // 0..1  (64-row group)
  const int colg = wave & 7;          // 0..7  (64-col group)
  const int l15  = lane & 15;
  const int lg   = lane >> 4;         // 0..3

  const bool is_enc = (wg * 128) < M_ENC;
  const float* __restrict__ Xg = is_enc ? enc : h0;
  const unsigned short* __restrict__ Wc = is_enc ? W1c : W5c;
  const float* __restrict__ Vg = is_enc ? W4 : W8;
  const int row0 = is_enc ? wg * 128 : wg * 128 - M_ENC;

  __shared__ char lds_raw[3 * BUFSZ + 4096];
  float* lred = (float*)(lds_raw + 3 * BUFSZ);   // [8][128]

  f4 acc[4][4];
#pragma unroll
  for (int i = 0; i < 4; ++i)
#pragma unroll
    for (int j = 0; j < 4; ++j) acc[i][j] = (f4){0.f, 0.f, 0.f, 0.f};

  // ---- A staging: thread -> (row, quad); 1 f4 load + 1 ds_write_b64 -------
  const int arow = tid >> 3;                     // 0..127
  const int aq   = tid & 7;                      // 0..7 (4 floats each)
  const float* aSrc = Xg + (size_t)(row0 + arow) * HH + aq * 4;
  const int aDst = arow * 72 + aq * 8;           // byte offset in A region

  // ---- fragment read bases -------------------------------------------------
  const int aRd = (rowg * 64 + l15) * 72 + lg * 16;          // A region
  const int bRd = ABYTES + colg * 4096 + lane * 16;          // B region

  f4 an;                                         // held A regs (next K-step)

#define ALOAD(kb_) do { an = *(const f4*)(aSrc + (kb_) * 32); } while (0)

#define AWR(bo_) do {                                                         \
    uint2 o_;                                                                 \
    o_.x = f2bu(an[0]) | (f2bu(an[1]) << 16);                                 \
    o_.y = f2bu(an[2]) | (f2bu(an[3]) << 16);                                 \
    *(uint2*)(lds_raw + (bo_) + aDst) = o_;                                   \
  } while (0)

#define BGLL(bo_, kb_) do {                                                   \
    _Pragma("unroll")                                                         \
    for (int p_ = 0; p_ < 2; ++p_) {                                          \
      const int idx_ = p_ * 1024 + tid;                                       \
      const char* gB_ = (const char*)Wc + (size_t)(kb_) * 32768 + idx_ * 16;  \
      char* lB_ = lds_raw + (bo_) + ABYTES + idx_ * 16;                       \
      __builtin_amdgcn_global_load_lds(                                       \
          (const __attribute__((address_space(1))) void*)gB_,                 \
          (__attribute__((address_space(3))) void*)lB_, 16, 0, 0);            \
    }                                                                         \
  } while (0)

#define COMPUTE(bo_) do {                                                     \
    const char* base_ = lds_raw + (bo_);                                      \
    short8 bfr_[4];                                                           \
    _Pragma("unroll")                                                         \
    for (int cf = 0; cf < 4; ++cf)                                            \
      bfr_[cf] = *(const short8*)(base_ + bRd + cf * 1024);                   \
    __builtin_amdgcn_s_setprio(1);                                            \
    _Pragma("unroll")                                                         \
    for (int rt = 0; rt < 4; ++rt) {                                          \
      short8 af_ = *(const short8*)(base_ + aRd + rt * 1152);                 \
      _Pragma("unroll")                                                       \
      for (int cf = 0; cf < 4; ++cf)                                          \
        acc[rt][cf] = __builtin_amdgcn_mfma_f32_16x16x32_bf16(af_, bfr_[cf],  \
                                                     acc[rt][cf], 0, 0, 0);   \
    }                                                                         \
    __builtin_amdgcn_s_setprio(0);                                            \
  } while (0)

#define SYNC3() do {                                                          \
    __builtin_amdgcn_sched_barrier(0);                                        \
    asm volatile("s_waitcnt vmcnt(3) lgkmcnt(0)" ::: "memory");               \
    __builtin_amdgcn_s_barrier();                                             \
    __builtin_amdgcn_sched_barrier(0);                                        \
  } while (0)

  // ---- prologue: stage kb=0; issue kb=1 ------------------------------------
  ALOAD(0);
  BGLL(0, 0);
  AWR(0);                 // compiler waits A(0) only (vmcnt(2): B(0) flies)
  ALOAD(1);
  BGLL(BUFSZ, 1);
  __builtin_amdgcn_sched_barrier(0);
  asm volatile("s_waitcnt vmcnt(3) lgkmcnt(0)" ::: "memory");  // drain B(0)
  __builtin_amdgcn_s_barrier();
  __builtin_amdgcn_sched_barrier(0);

  // ---- steady state: 10 triples, kb = 3t,3t+1,3t+2 (0..29) -----------------
#pragma unroll 1
  for (int t = 0; t < 10; ++t) {
    const int kb = 3 * t;
    // pos0: write A(kb+1)->buf1, issue kb+2->buf2, compute buf0
    AWR(BUFSZ); ALOAD(kb + 2); BGLL(2 * BUFSZ, kb + 2); COMPUTE(0); SYNC3();
    // pos1: write A(kb+2)->buf2, issue kb+3->buf0, compute buf1
    AWR(2 * BUFSZ); ALOAD(kb + 3); BGLL(0, kb + 3); COMPUTE(BUFSZ); SYNC3();
    // pos2: write A(kb+3)->buf0, issue kb+4->buf1, compute buf2
    AWR(0); ALOAD(kb + 4); BGLL(BUFSZ, kb + 4); COMPUTE(2 * BUFSZ); SYNC3();
  }
  // loop exits having computed kb=0..29; held regs = A(31); buf1 gll(31) in flight
  // epilogue: kb=30 (buf0), kb=31 (buf1)
  AWR(BUFSZ);             // write A(31); compiler waits A(31) only
  COMPUTE(0);             // kb=30
  __builtin_amdgcn_sched_barrier(0);
  asm volatile("s_waitcnt vmcnt(0) lgkmcnt(0)" ::: "memory");
  __builtin_amdgcn_s_barrier();
  __builtin_amdgcn_sched_barrier(0);
  COMPUTE(BUFSZ);         // kb=31
#undef ALOAD
#undef AWR
#undef BGLL
#undef COMPUTE
#undef SYNC3

  // epilogue: tanh, weight by V, reduce 16 lanes (cols), then across col-groups
  float vvv[4];
#pragma unroll
  for (int cf = 0; cf < 4; ++cf) vvv[cf] = Vg[colg * 64 + cf * 16 + l15];

#pragma unroll
  for (int rt = 0; rt < 4; ++rt) {
    float ps[4] = {0.f, 0.f, 0.f, 0.f};
#pragma unroll
    for (int cf = 0; cf < 4; ++cf) {
      const float w = vvv[cf];
#pragma unroll
      for (int r = 0; r < 4; ++r) ps[r] += w * tanh_fast(acc[rt][cf][r]);
    }
#pragma unroll
    for (int r = 0; r < 4; ++r) {
#pragma unroll
      for (int off = 1; off < 16; off <<= 1) ps[r] += __shfl_xor(ps[r], off);
    }
    if (l15 == 0) {
#pragma unroll
      for (int r = 0; r < 4; ++r)
        lred[colg * 128 + rowg * 64 + rt * 16 + lg * 4 + r] = ps[r];
    }
  }
  __syncthreads();
  if (tid < 128) {
    float s = 0.f;
#pragma unroll
    for (int c = 0; c < 8; ++c) s += lred[c * 128 + tid];
    e1[(size_t)wg * 128 + tid] = s;
  }
}

// ---------------- softmax over s + poly(ax) logit term + ax_new output -----
// logit[b][s] = e1[s*B+b] + x*(C0 + x^2*(C1 + x^2*C2)), x = ax[b,s]
__global__ void softmax_bs(const float* __restrict__ e1, const float* __restrict__ ax,
                           const float* __restrict__ C,
                           float* __restrict__ wout, float* __restrict__ axnew) {
  const int b = blockIdx.x, tid = threadIdx.x;  // 256 threads, 1024 elems
  const float c0 = C[0], c1 = C[1], c2 = C[2];
  __shared__ float red[256];
  float loc[4], xv[4];
  float m = -1e30f;
#pragma unroll
  for (int i = 0; i < 4; ++i) {
    const int s = i * 256 + tid;
    const float x = ax[b * SS + s];
    const float x2 = x * x;
    xv[i] = x;
    loc[i] = e1[s * BB + b] + x * (c0 + x2 * (c1 + x2 * c2));
    m = fmaxf(m, loc[i]);
  }
  red[tid] = m; __syncthreads();
  for (int off = 128; off > 0; off >>= 1) {
    if (tid < off) red[tid] = fmaxf(red[tid], red[tid + off]);
    __syncthreads();
  }
  m = red[0]; __syncthreads();
  float sum = 0.f;
#pragma unroll
  for (int i = 0; i < 4; ++i) { loc[i] = __expf(loc[i] - m); sum += loc[i]; }
  red[tid] = sum; __syncthreads();
  for (int off = 128; off > 0; off >>= 1) {
    if (tid < off) red[tid] += red[tid + off];
    __syncthreads();
  }
  const float inv = 1.f / red[0];
#pragma unroll
  for (int i = 0; i < 4; ++i) {
    const int s = i * 256 + tid;
    const float a_ = loc[i] * inv;
    wout[b * SS + s] = a_;
    axnew[b * SS + s] = xv[i] + a_;
  }
}

// ---------------- softmax over t, input layout [t][b] strided ----------------
__global__ void softmax_tb(const float* __restrict__ ein, float* __restrict__ wout) {
  const int b = blockIdx.x, tid = threadIdx.x;
  __shared__ float red[256];
  float loc[4];
  float m = -1e30f;
#pragma unroll
  for (int i = 0; i < 4; ++i) { loc[i] = ein[(i * 256 + tid) * BB + b]; m = fmaxf(m, loc[i]); }
  red[tid] = m; __syncthreads();
  for (int off = 128; off > 0; off >>= 1) {
    if (tid < off) red[tid] = fmaxf(red[tid], red[tid + off]);
    __syncthreads();
  }
  m = red[0]; __syncthreads();
  float sum = 0.f;
#pragma unroll
  for (int i = 0; i < 4; ++i) { loc[i] = __expf(loc[i] - m); sum += loc[i]; }
  red[tid] = sum; __syncthreads();
  for (int off = 128; off > 0; off >>= 1) {
    if (tid < off) red[tid] += red[tid + off];
    __syncthreads();
  }
  const float inv = 1.f / red[0];
#pragma unroll
  for (int i = 0; i < 4; ++i) wout[b * TN + (i * 256 + tid)] = loc[i] * inv;
}

// ---------------- chunked weighted sum: part[b][ch][h] = sum_{s in ch} w[b,s]*X[s,b,h] ------------
__global__ void wpart(const float* __restrict__ X, const float* __restrict__ w,
                      float* __restrict__ part) {
  const int b = blockIdx.x / NCH, ch = blockIdx.x % NCH;
  const int tid = threadIdx.x;  // 256, each handles 4 h
  __shared__ float ws[SS / NCH];
  if (tid < SS / NCH) ws[tid] = w[b * SS + ch * (SS / NCH) + tid];
  __syncthreads();
  f4 acc = (f4){0.f, 0.f, 0.f, 0.f};
  const float* base = X + ((size_t)(ch * (SS / NCH)) * BB + b) * HH + tid * 4;
#pragma unroll 4
  for (int i = 0; i < SS / NCH; ++i) {
    f4 x = *(const f4*)(base + (size_t)i * BB * HH);
    acc += ws[i] * x;
  }
  *(f4*)&part[((size_t)(b * NCH + ch)) * HH + tid * 4] = acc;
}

__global__ void wreduce(const float* __restrict__ part, float* __restrict__ out) {
  const int idx = blockIdx.x * 256 + threadIdx.x;  // over B*H
  const int b = idx / HH, h = idx % HH;
  float s = 0.f;
#pragma unroll
  for (int ch = 0; ch < NCH; ++ch) s += part[((size_t)(b * NCH + ch)) * HH + h];
  out[idx] = s;
}

// ---------------- zi[b] = sigmoid( cxi[b,:].W11[0:H] + cti[b,:].W11[H:2H] ) ----------------
__global__ void zi_kernel(const float* __restrict__ cxi, const float* __restrict__ cti,
                          const float* __restrict__ W11, float* __restrict__ zi) {
  const int b = blockIdx.x, tid = threadIdx.x;  // 256
  float s = 0.f;
  for (int i = tid; i < HH; i += 256) s += cxi[b * HH + i] * W11[i] + cti[b * HH + i] * W11[HH + i];
  __shared__ float red[4];
  for (int off = 32; off > 0; off >>= 1) s += __shfl_down(s, off);
  if ((tid & 63) == 0) red[tid >> 6] = s;
  __syncthreads();
  if (tid == 0) {
    float t = red[0] + red[1] + red[2] + red[3];
    zi[b] = 1.f / (1.f + __expf(-t));
  }
}

// ---------------- ci[b,h] = z*tanh(cxi.W9[h,:]) + (1-z)*tanh(cti.W10[h,:]) ----------------
__global__ void ci_kernel(const float* __restrict__ cxi, const float* __restrict__ cti,
                          const float* __restrict__ W9, const float* __restrict__ W10,
                          const float* __restrict__ zi, float* __restrict__ out_ci) {
  const int b = blockIdx.x >> 2, hb = blockIdx.x & 3, tid = threadIdx.x;
  const int h = hb * 256 + tid;
  __shared__ float cx[HH], ct[HH];
  for (int i = tid; i < HH; i += 256) { cx[i] = cxi[b * HH + i]; ct[i] = cti[b * HH + i]; }
  __syncthreads();
  const float* __restrict__ w9r  = W9  + (size_t)h * HH;
  const float* __restrict__ w10r = W10 + (size_t)h * HH;
  float gx = 0.f, gt = 0.f;
  for (int k = 0; k < HH; k += 4) {
    f4 a = *(const f4*)(w9r + k);
    f4 c = *(const f4*)(w10r + k);
    gx += cx[k] * a[0] + cx[k + 1] * a[1] + cx[k + 2] * a[2] + cx[k + 3] * a[3];
    gt += ct[k] * c[0] + ct[k + 1] * c[1] + ct[k + 2] * c[2] + ct[k + 3] * c[3];
  }
  const float z = zi[b];
  out_ci[b * HH + h] = z * tanhf(gx) + (1.f - z) * tanhf(gt);
}

extern "C" void kernel_launch(void* const* d_in, const int* in_sizes, int n_in,
                              void* d_out, int out_size, void* d_ws, size_t ws_size,
                              hipStream_t stream) {
  const float* enc = (const float*)d_in[1];
  const float* h0  = (const float*)d_in[2];
  const float* ax  = (const float*)d_in[3];
  const float* W1  = (const float*)d_in[4];
  const float* W3  = (const float*)d_in[6];
  const float* W4  = (const float*)d_in[7];
  const float* W5  = (const float*)d_in[8];
  const float* W8  = (const float*)d_in[11];
  const float* W9  = (const float*)d_in[12];
  const float* W10 = (const float*)d_in[13];
  const float* W11 = (const float*)d_in[14];
  float* out = (float*)d_out;  // [0:B*H) ci, [B*H : 2*B*H) ax_new

  // Workspace layout (floats). W1c/W5c each 512*1024 bf16 = 262144 floats (1MB).
  // partx/partt ALIAS the Wc regions: Wc dead after e1_gemm; wprep recreates
  // Wc at the start of every call (deterministic across graph replays).
  float* w = (float*)d_ws;
  unsigned short* W1c = (unsigned short*)w;            // floats [0, 262144)
  unsigned short* W5c = (unsigned short*)(w + 262144); // floats [262144, 524288)
  float* partx = w;                  // aliases W1c
  float* partt = w + 262144;         // aliases W5c
  float* e1    = w + 524288;         // 65536
  float* axi   = w + 589824;         // 32768
  float* ati   = w + 622592;         // 32768
  float* cxi   = w + 655360;         // 32768
  float* cti   = w + 688128;         // 32768
  float* zi    = w + 720896;         // 64
  float* Cpoly = w + 720960;         // 16   (end: ~2.88 MB)

  wprep<<<256, 256, 0, stream>>>(W1, W1c);
  wprep<<<256, 256, 0, stream>>>(W5, W5c);
  poly_prep<<<1, 512, 0, stream>>>(W3, W4, Cpoly);
  e1_gemm<<<M_TOT / 128, 1024, 0, stream>>>(enc, h0, W1c, W5c, W4, W8, e1);
  softmax_bs<<<BB, 256, 0, stream>>>(e1, ax, Cpoly, axi, out + BB * HH);
  softmax_tb<<<BB, 256, 0, stream>>>(e1 + M_ENC, ati);
  wpart<<<BB * NCH, 256, 0, stream>>>(enc, axi, partx);
  wpart<<<BB * NCH, 256, 0, stream>>>(h0, ati, partt);
  wreduce<<<BB * HH / 256, 256, 0, stream>>>(partx, cxi);
  wreduce<<<BB * HH / 256, 256, 0, stream>>>(partt, cti);
  zi_kernel<<<BB, 256, 0, stream>>>(cxi, cti, W11, zi);
  ci_kernel<<<BB * 4, 256, 0, stream>>>(cxi, cti, W9, W10, zi, out);
}

// Round 9
// 224.470 us; speedup vs baseline: 1.2919x; 1.2919x over previous
//
#include <hip/hip_runtime.h>
#include <hip/hip_bf16.h>

#define HH 1024
#define AA 512
#define BB 32
#define SS 1024
#define TN 1024
#define M_ENC (SS*BB)
#define M_TOT ((SS+TN)*BB)
#define NCH 8

// e1_gemm LDS geometry: buffer = [A 64x64B = 4KB][B 32KB] = 36864 B, x2 = 72KB
#define ABYTES 4096
#define BUFSZ  36864

typedef __attribute__((ext_vector_type(8))) short short8;
typedef __attribute__((ext_vector_type(4))) float f4;

union bfu { __hip_bfloat16 h; unsigned short u; };
__device__ __forceinline__ unsigned int f2bu(float x) {
  bfu t; t.h = __float2bfloat16(x); return (unsigned int)t.u;
}
__device__ __forceinline__ unsigned short f2b(float x) {
  bfu t; t.h = __float2bfloat16(x); return t.u;
}
__device__ __forceinline__ float tanh_fast(float x) {
  float e = __expf(2.f * x);
  return 1.f - 2.f / (e + 1.f);
}

// ---- one-time W -> bf16 fragment-order repack ------------------------------
// Wc layout: frag id t = ((kb*32 + rg)*64 + lane), 8 bf16 per frag.
// fragment holds W[rg*16 + (lane&15)][kb*32 + (lane>>4)*8 + j]
__global__ void wprep(const float* __restrict__ W, unsigned short* __restrict__ Wc) {
  const int t = blockIdx.x * 256 + threadIdx.x;     // 0..65535
  const int lane = t & 63;
  const int rg = (t >> 6) & 31;
  const int kb = t >> 11;
  const int row = rg * 16 + (lane & 15);
  const int k = kb * 32 + ((lane >> 4) << 3);
  const float* src = W + (size_t)row * HH + k;
  f4 v0 = *(const f4*)(src);
  f4 v1 = *(const f4*)(src + 4);
  short8 o;
  o[0] = f2b(v0[0]); o[1] = f2b(v0[1]); o[2] = f2b(v0[2]); o[3] = f2b(v0[3]);
  o[4] = f2b(v1[0]); o[5] = f2b(v1[1]); o[6] = f2b(v1[2]); o[7] = f2b(v1[3]);
  *(short8*)(Wc + (size_t)t * 8) = o;
}

// ---- poly coefficients: sum_a W4[2A+a]*tanh(x*W3[a]) = C0*x + C1*x^3 + C2*x^5
__global__ void poly_prep(const float* __restrict__ W3, const float* __restrict__ W4,
                          float* __restrict__ C) {
  __shared__ float r1[AA], r3[AA], r5[AA];
  const int a = threadIdx.x;  // 512
  const float w = W3[a], u = W4[2 * AA + a];
  const float w2 = w * w;
  r1[a] = u * w;
  r3[a] = u * w * w2;
  r5[a] = u * w * w2 * w2;
  __syncthreads();
  for (int off = 256; off > 0; off >>= 1) {
    if (a < off) { r1[a] += r1[a + off]; r3[a] += r3[a + off]; r5[a] += r5[a + off]; }
    __syncthreads();
  }
  if (a == 0) { C[0] = r1[0]; C[1] = -r3[0] / 3.f; C[2] = r5[0] * (2.f / 15.f); }
}

// ---- big fused GEMM: e1[row] = sum_a V[a]*tanh( X[row,:] . W[a,:] ) --------
// BM=64, 512 threads = 8 waves (1 rowg x 8 colg), wave tile 64x64, acc[4][4].
// LDS 72KB -> 2 blocks/CU: TWO independent barrier domains per CU, so one
// block's __syncthreads drain is covered by the sibling block's compute
// (m97/m114 mechanism). Simple 2-buffer loop, unrolled x2 for static offsets.
// A: reg-staged fp32->bf16->ds_write, 64B stride + XOR swizzle (r7: 0 confl).
// B: fragment-ordered bf16 via global_load_lds (linear).
// Epilogue writes e1 TRANSPOSED: e1s[b][s] / e1t[b][t] so both softmax
// kernels read coalesced.
__global__ __launch_bounds__(512, 4)
void e1_gemm(const float* __restrict__ enc, const float* __restrict__ h0,
             const unsigned short* __restrict__ W1c, const unsigned short* __restrict__ W5c,
             const float* __restrict__ W4, const float* __restrict__ W8,
             float* __restrict__ e1s, float* __restrict__ e1t) {
  const int wg   = blockIdx.x;        // 1024 blocks, 64 rows each
  const int tid  = threadIdx.x;       // 512
  const int lane = tid & 63;
  const int colg = tid >> 6;          // 0..7 (64-col group)
  const int l15  = lane & 15;
  const int lg   = lane >> 4;         // 0..3

  const bool is_enc = (wg * 64) < M_ENC;
  const float* __restrict__ Xg = is_enc ? enc : h0;
  const unsigned short* __restrict__ Wc = is_enc ? W1c : W5c;
  const float* __restrict__ Vg = is_enc ? W4 : W8;
  const int row0 = is_enc ? wg * 64 : wg * 64 - M_ENC;

  __shared__ char lds_raw[2 * BUFSZ];
  float* lred = (float*)lds_raw;      // [8][64] floats, epilogue only

  f4 acc[4][4];
#pragma unroll
  for (int i = 0; i < 4; ++i)
#pragma unroll
    for (int j = 0; j < 4; ++j) acc[i][j] = (f4){0.f, 0.f, 0.f, 0.f};

  // ---- A staging: thread -> (row, quad); 1 f4 load + 1 8B ds_write ---------
  const int arow = tid >> 3;                     // 0..63
  const int aq   = tid & 7;                      // 0..7 (4 floats each)
  const float* aSrc = Xg + (size_t)(row0 + arow) * HH + aq * 4;
  const int slotS = (aq >> 1) ^ ((arow >> 1) & 3);
  const int aDst = arow * 64 + slotS * 16 + (aq & 1) * 8;

  // ---- fragment read bases -------------------------------------------------
  const int aRd = l15 * 64 + ((lg ^ ((l15 >> 1) & 3)) << 4);  // + rt*1024
  const int bRd = ABYTES + colg * 4096 + lane * 16;           // + cf*1024

  f4 an;                                          // held A regs (next K-step)

#define ALOAD(kb_) do { an = *(const f4*)(aSrc + (kb_) * 32); } while (0)

#define AWR(bo_) do {                                                         \
    uint2 o_;                                                                 \
    o_.x = f2bu(an[0]) | (f2bu(an[1]) << 16);                                 \
    o_.y = f2bu(an[2]) | (f2bu(an[3]) << 16);                                 \
    *(uint2*)(lds_raw + (bo_) + aDst) = o_;                                   \
  } while (0)

#define BGLL(bo_, kb_) do {                                                   \
    _Pragma("unroll")                                                         \
    for (int p_ = 0; p_ < 4; ++p_) {                                          \
      const int idx_ = p_ * 512 + tid;                                        \
      const char* gB_ = (const char*)Wc + (size_t)(kb_) * 32768 + idx_ * 16;  \
      char* lB_ = lds_raw + (bo_) + ABYTES + idx_ * 16;                       \
      __builtin_amdgcn_global_load_lds(                                       \
          (const __attribute__((address_space(1))) void*)gB_,                 \
          (__attribute__((address_space(3))) void*)lB_, 16, 0, 0);            \
    }                                                                         \
  } while (0)

#define COMPUTE(bo_) do {                                                     \
    const char* base_ = lds_raw + (bo_);                                      \
    short8 bfr_[4];                                                           \
    _Pragma("unroll")                                                         \
    for (int cf = 0; cf < 4; ++cf)                                            \
      bfr_[cf] = *(const short8*)(base_ + bRd + cf * 1024);                   \
    __builtin_amdgcn_s_setprio(1);                                            \
    _Pragma("unroll")                                                         \
    for (int rt = 0; rt < 4; ++rt) {                                          \
      short8 af_ = *(const short8*)(base_ + aRd + rt * 1024);                 \
      _Pragma("unroll")                                                       \
      for (int cf = 0; cf < 4; ++cf)                                          \
        acc[rt][cf] = __builtin_amdgcn_mfma_f32_16x16x32_bf16(af_, bfr_[cf],  \
                                                     acc[rt][cf], 0, 0, 0);   \
    }                                                                         \
    __builtin_amdgcn_s_setprio(0);                                            \
  } while (0)

  // ---- prologue: stage kb=0 ------------------------------------------------
  ALOAD(0);
  BGLL(0, 0);
  AWR(0);
  __syncthreads();

  // ---- main loop: 2-buffer, unrolled x2 (static offsets) -------------------
#pragma unroll 1
  for (int it = 0; it < 15; ++it) {
    ALOAD(2 * it + 1); BGLL(BUFSZ, 2 * it + 1); COMPUTE(0);     AWR(BUFSZ);
    __syncthreads();
    ALOAD(2 * it + 2); BGLL(0, 2 * it + 2);     COMPUTE(BUFSZ); AWR(0);
    __syncthreads();
  }
  ALOAD(31); BGLL(BUFSZ, 31); COMPUTE(0); AWR(BUFSZ);
  __syncthreads();
  COMPUTE(BUFSZ);
#undef ALOAD
#undef AWR
#undef BGLL
#undef COMPUTE

  // epilogue: tanh, weight by V, reduce 16 col-lanes, then across col-groups
  float vvv[4];
#pragma unroll
  for (int cf = 0; cf < 4; ++cf) vvv[cf] = Vg[colg * 64 + cf * 16 + l15];

  __syncthreads();   // buffers dead; lred aliases buf0
#pragma unroll
  for (int rt = 0; rt < 4; ++rt) {
    float ps[4] = {0.f, 0.f, 0.f, 0.f};
#pragma unroll
    for (int cf = 0; cf < 4; ++cf) {
      const float w = vvv[cf];
#pragma unroll
      for (int r = 0; r < 4; ++r) ps[r] += w * tanh_fast(acc[rt][cf][r]);
    }
#pragma unroll
    for (int r = 0; r < 4; ++r) {
#pragma unroll
      for (int off = 1; off < 16; off <<= 1) ps[r] += __shfl_xor(ps[r], off);
    }
    if (l15 == 0) {
#pragma unroll
      for (int r = 0; r < 4; ++r)
        lred[colg * 64 + rt * 16 + lg * 4 + r] = ps[r];
    }
  }
  __syncthreads();
  if (tid < 64) {
    float s = 0.f;
#pragma unroll
    for (int c = 0; c < 8; ++c) s += lred[c * 64 + tid];
    const int gr = row0 + tid;
    const int q = gr >> 5;            // s or t index
    const int b = gr & 31;
    if (is_enc) e1s[b * SS + q] = s;
    else        e1t[b * TN + q] = s;
  }
}

// ---------------- softmax over s + poly(ax) logit term + ax_new output -----
// logit[b][s] = e1s[b][s] + x*(C0 + x^2*(C1 + x^2*C2)), x = ax[b,s]
__global__ void softmax_bs(const float* __restrict__ e1s, const float* __restrict__ ax,
                           const float* __restrict__ C,
                           float* __restrict__ wout, float* __restrict__ axnew) {
  const int b = blockIdx.x, tid = threadIdx.x;  // 256 threads, 1024 elems
  const float c0 = C[0], c1 = C[1], c2 = C[2];
  __shared__ float red[256];
  float loc[4], xv[4];
  float m = -1e30f;
#pragma unroll
  for (int i = 0; i < 4; ++i) {
    const int s = i * 256 + tid;
    const float x = ax[b * SS + s];
    const float x2 = x * x;
    xv[i] = x;
    loc[i] = e1s[b * SS + s] + x * (c0 + x2 * (c1 + x2 * c2));
    m = fmaxf(m, loc[i]);
  }
  red[tid] = m; __syncthreads();
  for (int off = 128; off > 0; off >>= 1) {
    if (tid < off) red[tid] = fmaxf(red[tid], red[tid + off]);
    __syncthreads();
  }
  m = red[0]; __syncthreads();
  float sum = 0.f;
#pragma unroll
  for (int i = 0; i < 4; ++i) { loc[i] = __expf(loc[i] - m); sum += loc[i]; }
  red[tid] = sum; __syncthreads();
  for (int off = 128; off > 0; off >>= 1) {
    if (tid < off) red[tid] += red[tid + off];
    __syncthreads();
  }
  const float inv = 1.f / red[0];
#pragma unroll
  for (int i = 0; i < 4; ++i) {
    const int s = i * 256 + tid;
    const float a_ = loc[i] * inv;
    wout[b * SS + s] = a_;
    axnew[b * SS + s] = xv[i] + a_;
  }
}

// ---------------- softmax over t, coalesced e1t[b][t] ----------------------
__global__ void softmax_tb(const float* __restrict__ e1t, float* __restrict__ wout) {
  const int b = blockIdx.x, tid = threadIdx.x;
  __shared__ float red[256];
  float loc[4];
  float m = -1e30f;
#pragma unroll
  for (int i = 0; i < 4; ++i) { loc[i] = e1t[b * TN + i * 256 + tid]; m = fmaxf(m, loc[i]); }
  red[tid] = m; __syncthreads();
  for (int off = 128; off > 0; off >>= 1) {
    if (tid < off) red[tid] = fmaxf(red[tid], red[tid + off]);
    __syncthreads();
  }
  m = red[0]; __syncthreads();
  float sum = 0.f;
#pragma unroll
  for (int i = 0; i < 4; ++i) { loc[i] = __expf(loc[i] - m); sum += loc[i]; }
  red[tid] = sum; __syncthreads();
  for (int off = 128; off > 0; off >>= 1) {
    if (tid < off) red[tid] += red[tid + off];
    __syncthreads();
  }
  const float inv = 1.f / red[0];
#pragma unroll
  for (int i = 0; i < 4; ++i) wout[b * TN + (i * 256 + tid)] = loc[i] * inv;
}

// ---------------- chunked weighted sum: part[b][ch][h] = sum_{s in ch} w[b,s]*X[s,b,h] ------------
__global__ void wpart(const float* __restrict__ X, const float* __restrict__ w,
                      float* __restrict__ part) {
  const int b = blockIdx.x / NCH, ch = blockIdx.x % NCH;
  const int tid = threadIdx.x;  // 256, each handles 4 h
  __shared__ float ws[SS / NCH];
  if (tid < SS / NCH) ws[tid] = w[b * SS + ch * (SS / NCH) + tid];
  __syncthreads();
  f4 acc = (f4){0.f, 0.f, 0.f, 0.f};
  const float* base = X + ((size_t)(ch * (SS / NCH)) * BB + b) * HH + tid * 4;
#pragma unroll 4
  for (int i = 0; i < SS / NCH; ++i) {
    f4 x = *(const f4*)(base + (size_t)i * BB * HH);
    acc += ws[i] * x;
  }
  *(f4*)&part[((size_t)(b * NCH + ch)) * HH + tid * 4] = acc;
}

__global__ void wreduce(const float* __restrict__ part, float* __restrict__ out) {
  const int idx = blockIdx.x * 256 + threadIdx.x;  // over B*H
  const int b = idx / HH, h = idx % HH;
  float s = 0.f;
#pragma unroll
  for (int ch = 0; ch < NCH; ++ch) s += part[((size_t)(b * NCH + ch)) * HH + h];
  out[idx] = s;
}

// ---------------- zi[b] = sigmoid( cxi[b,:].W11[0:H] + cti[b,:].W11[H:2H] ) ----------------
__global__ void zi_kernel(const float* __restrict__ cxi, const float* __restrict__ cti,
                          const float* __restrict__ W11, float* __restrict__ zi) {
  const int b = blockIdx.x, tid = threadIdx.x;  // 256
  float s = 0.f;
  for (int i = tid; i < HH; i += 256) s += cxi[b * HH + i] * W11[i] + cti[b * HH + i] * W11[HH + i];
  __shared__ float red[4];
  for (int off = 32; off > 0; off >>= 1) s += __shfl_down(s, off);
  if ((tid & 63) == 0) red[tid >> 6] = s;
  __syncthreads();
  if (tid == 0) {
    float t = red[0] + red[1] + red[2] + red[3];
    zi[b] = 1.f / (1.f + __expf(-t));
  }
}

// ---------------- ci[b,h] = z*tanh(cxi.W9[h,:]) + (1-z)*tanh(cti.W10[h,:]) ----------------
__global__ void ci_kernel(const float* __restrict__ cxi, const float* __restrict__ cti,
                          const float* __restrict__ W9, const float* __restrict__ W10,
                          const float* __restrict__ zi, float* __restrict__ out_ci) {
  const int b = blockIdx.x >> 2, hb = blockIdx.x & 3, tid = threadIdx.x;
  const int h = hb * 256 + tid;
  __shared__ float cx[HH], ct[HH];
  for (int i = tid; i < HH; i += 256) { cx[i] = cxi[b * HH + i]; ct[i] = cti[b * HH + i]; }
  __syncthreads();
  const float* __restrict__ w9r  = W9  + (size_t)h * HH;
  const float* __restrict__ w10r = W10 + (size_t)h * HH;
  float gx = 0.f, gt = 0.f;
  for (int k = 0; k < HH; k += 4) {
    f4 a = *(const f4*)(w9r + k);
    f4 c = *(const f4*)(w10r + k);
    gx += cx[k] * a[0] + cx[k + 1] * a[1] + cx[k + 2] * a[2] + cx[k + 3] * a[3];
    gt += ct[k] * c[0] + ct[k + 1] * c[1] + ct[k + 2] * c[2] + ct[k + 3] * c[3];
  }
  const float z = zi[b];
  out_ci[b * HH + h] = z * tanhf(gx) + (1.f - z) * tanhf(gt);
}

extern "C" void kernel_launch(void* const* d_in, const int* in_sizes, int n_in,
                              void* d_out, int out_size, void* d_ws, size_t ws_size,
                              hipStream_t stream) {
  const float* enc = (const float*)d_in[1];
  const float* h0  = (const float*)d_in[2];
  const float* ax  = (const float*)d_in[3];
  const float* W1  = (const float*)d_in[4];
  const float* W3  = (const float*)d_in[6];
  const float* W4  = (const float*)d_in[7];
  const float* W5  = (const float*)d_in[8];
  const float* W8  = (const float*)d_in[11];
  const float* W9  = (const float*)d_in[12];
  const float* W10 = (const float*)d_in[13];
  const float* W11 = (const float*)d_in[14];
  float* out = (float*)d_out;  // [0:B*H) ci, [B*H : 2*B*H) ax_new

  // Workspace layout (floats). W1c/W5c each 512*1024 bf16 = 262144 floats (1MB).
  // partx/partt ALIAS the Wc regions: Wc dead after e1_gemm; wprep recreates
  // Wc at the start of every call (deterministic across graph replays).
  float* w = (float*)d_ws;
  unsigned short* W1c = (unsigned short*)w;            // floats [0, 262144)
  unsigned short* W5c = (unsigned short*)(w + 262144); // floats [262144, 524288)
  float* partx = w;                  // aliases W1c
  float* partt = w + 262144;         // aliases W5c
  float* e1s   = w + 524288;         // 32768 (transposed [b][s])
  float* e1t   = w + 557056;         // 32768 (transposed [b][t])
  float* axi   = w + 589824;         // 32768
  float* ati   = w + 622592;         // 32768
  float* cxi   = w + 655360;         // 32768
  float* cti   = w + 688128;         // 32768
  float* zi    = w + 720896;         // 64
  float* Cpoly = w + 720960;         // 16   (end: ~2.88 MB)

  wprep<<<256, 256, 0, stream>>>(W1, W1c);
  wprep<<<256, 256, 0, stream>>>(W5, W5c);
  poly_prep<<<1, 512, 0, stream>>>(W3, W4, Cpoly);
  e1_gemm<<<M_TOT / 64, 512, 0, stream>>>(enc, h0, W1c, W5c, W4, W8, e1s, e1t);
  softmax_bs<<<BB, 256, 0, stream>>>(e1s, ax, Cpoly, axi, out + BB * HH);
  softmax_tb<<<BB, 256, 0, stream>>>(e1t, ati);
  wpart<<<BB * NCH, 256, 0, stream>>>(enc, axi, partx);
  wpart<<<BB * NCH, 256, 0, stream>>>(h0, ati, partt);
  wreduce<<<BB * HH / 256, 256, 0, stream>>>(partx, cxi);
  wreduce<<<BB * HH / 256, 256, 0, stream>>>(partt, cti);
  zi_kernel<<<BB, 256, 0, stream>>>(cxi, cti, W11, zi);
  ci_kernel<<<BB * 4, 256, 0, stream>>>(cxi, cti, W9, W10, zi, out);
}